// Round 14
// baseline (331.649 us; speedup 1.0000x reference)
//
#include <hip/hip_runtime.h>
#include <hip/hip_bf16.h>

#define NN 25000
#define NE 100000
#define FIN 32
#define DD 64
#define NG 1000

typedef unsigned short u16;
typedef __attribute__((ext_vector_type(8))) short short8;
typedef __attribute__((ext_vector_type(4))) float f32x4;

__device__ __forceinline__ float b2f(u16 u) {
    union { unsigned int i; float f; } v; v.i = ((unsigned int)u) << 16; return v.f;
}
__device__ __forceinline__ u16 f2b(float f) {
    __hip_bfloat16 h = __float2bfloat16(f);
    return __builtin_bit_cast(u16, h);
}
// edge_index may be int64 read as int32 words: odd words would all be 0.
__device__ __forceinline__ bool idx_is_i64(const int* e) {
    return (e[1] == 0) & (e[3] == 0) & (e[5] == 0) & (e[7] == 0) & (e[9] == 0);
}
__device__ __forceinline__ int ld_src(const int* e, int i, bool i64) {
    return i64 ? e[2 * i] : e[i];
}
__device__ __forceinline__ int ld_dst(const int* e, int i, bool i64) {
    return i64 ? e[2 * (NE + i)] : e[NE + i];
}

// ---- fused pre-pass: blocks [0,6250) = lin0; blocks [6250,7274) = Bt2 build + zeroing ----
// Bt2 fragment-major: idx = kc*4096 + (s*4+c)*512 + lane*8 + j  holds
// B[k = kc*64 + s*32 + (lane>>4)*8 + j][o = c*16 + (lane&15)]  (r>=4096 -> be2 rows).
__global__ __launch_bounds__(256) void k_pre(const float* __restrict__ x,
                                             const float* __restrict__ W0,
                                             const float* __restrict__ b0,
                                             u16* __restrict__ x1b,
                                             const float* __restrict__ We2,
                                             const float* __restrict__ be2,
                                             float* __restrict__ agg,
                                             float* __restrict__ pooled,
                                             u16* __restrict__ Bt2) {
    __shared__ float sW[FIN * DD];
    __shared__ float sx[4 * FIN];
    if (blockIdx.x < 6250) {
        int tid = threadIdx.x;
        for (int i = tid; i < FIN * DD; i += 256) sW[i] = W0[i];
        int nbase = blockIdx.x * 4;
        for (int i = tid; i < 4 * FIN; i += 256) {
            int nl = i >> 5, f = i & 31;
            int n = nbase + nl;
            sx[i] = (n < NN) ? x[n * FIN + f] : 0.f;
        }
        __syncthreads();
        int lane = tid & 63, nl = tid >> 6;
        int n = nbase + nl;
        if (n < NN) {
            float acc = b0[lane];
            #pragma unroll
            for (int f = 0; f < FIN; f++) acc += sx[nl * FIN + f] * sW[f * DD + lane];
            x1b[n * DD + lane] = f2b(fmaxf(acc, 0.f));
        }
    } else {
        int tid = (blockIdx.x - 6250) * 256 + threadIdx.x;
        int stride = 1024 * 256;
        for (int idx = tid; idx < 65 * 4096; idx += stride) {
            int kc = idx >> 12;
            int rem = idx & 4095;
            int f = rem >> 9;
            int ln = (rem >> 3) & 63;
            int j = idx & 7;
            int s = f >> 2, c = f & 3;
            int o = c * 16 + (ln & 15);
            int r = kc * 64 + s * 32 + (ln >> 4) * 8 + j;
            float v = (r < 4096) ? We2[(r >> 6) * 4096 + (r & 63) * 64 + o]
                                 : be2[(r - 4096) * 64 + o];
            Bt2[idx] = f2b(v);
        }
        for (int idx = tid; idx < NN * DD; idx += stride) agg[idx] = 0.f;
        for (int idx = tid; idx < NG * DD; idx += stride) pooled[idx] = 0.f;
    }
}

// ---- fused NNConv message GEMM + scatter -------------------------------------------------
// 512 threads = 8 waves: wave = (row-half rh, col-quarter cq). Per kc: q = Xs@W2[kc]
// (bf16 MFMA, fixed A-frags), msg += t[e,kc]*q. B direct from L2-resident Bt2 (coalesced,
// depth-1 register prefetch); K-loop barrier-free. sX and sT ALIAS the same LDS region
// (A-frags hoisted before t is computed): LDS = 18432 + 2048 + 256 + 512 = 21248 B
// -> LDS allows 7 blocks/CU; wave cap 32/CU -> 4 blocks. launch_bounds(512,8) caps VGPR
// at 64 so the full 32-wave residency is reachable (r13 measured 44 VGPR).
__global__ __launch_bounds__(512, 8) void k_msg(const float* __restrict__ ea,
                                                const int* __restrict__ eidx,
                                                const float* __restrict__ We1,
                                                const float* __restrict__ be1,
                                                const u16* __restrict__ x1b,
                                                const u16* __restrict__ Bt2,
                                                float* __restrict__ agg) {
    __shared__ __align__(16) u16 sXT[128 * 72];  // phase1: sX rows; K-loop: sT bf16 [64][128]
    __shared__ float sWe1[8 * 64];
    __shared__ float sbe1[64];
    __shared__ int sDst[128];
    const int tid = threadIdx.x;
    const int lane = tid & 63, wv = tid >> 6;
    const int ll = lane & 15, quad = lane >> 4;
    const int rh = wv >> 2, cq = wv & 3;       // row-half, col-quarter
    const int e0 = blockIdx.x * 128;
    const bool i64 = idx_is_i64(eidx);
    u16* sX = sXT;
    u16* sT = sXT;   // alias: sX is dead once A-fragments are hoisted

    if (tid < 512) sWe1[tid] = We1[tid];
    if (tid < 64) sbe1[tid] = be1[tid];
    if (tid < 128) sDst[tid] = (e0 + tid < NE) ? ld_dst(eidx, e0 + tid, i64) : 0;

    // phase 1: gather x1 rows (bf16) for 128 edges; each thread: 32 B of one row
    const int el4 = tid >> 2, seg = tid & 3;
    const int eg4 = e0 + el4;
    {
        if (eg4 < NE) {
            int sv = ld_src(eidx, eg4, i64);
            const u16* xr = x1b + sv * 64 + seg * 16;
            *(uint4*)&sX[el4 * 72 + seg * 16]     = *(const uint4*)(xr);
            *(uint4*)&sX[el4 * 72 + seg * 16 + 8] = *(const uint4*)(xr + 8);
        } else {
            uint4 z = make_uint4(0, 0, 0, 0);
            *(uint4*)&sX[el4 * 72 + seg * 16]     = z;
            *(uint4*)&sX[el4 * 72 + seg * 16 + 8] = z;
        }
    }
    float eav[8];
    if (eg4 < NE) {
        f32x4 v0 = *(const f32x4*)(ea + eg4 * 8);
        f32x4 v1 = *(const f32x4*)(ea + eg4 * 8 + 4);
        #pragma unroll
        for (int f = 0; f < 4; f++) { eav[f] = v0[f]; eav[4 + f] = v1[f]; }
    } else {
        #pragma unroll
        for (int f = 0; f < 8; f++) eav[f] = 0.f;
    }
    __syncthreads();

    // hoist fixed A-fragments BEFORE phase 2 (sT will overwrite sX)
    short8 xa[4][2];
    #pragma unroll
    for (int rt = 0; rt < 4; rt++)
        #pragma unroll
        for (int s = 0; s < 2; s++)
            xa[rt][s] = *(const short8*)&sX[(rh * 64 + rt * 16 + ll) * 72 + s * 32 + quad * 8];
    __syncthreads();   // all hoists complete before sT writes trample sX

    // phase 2: t[e,k] = relu(ea @ We1 + be1); each thread: 16 k-values of its edge (bf16)
    {
        int k0 = seg * 16;
        for (int kk = 0; kk < 16; kk++) {
            int k = k0 + kk;
            float acc = sbe1[k];
            #pragma unroll
            for (int f = 0; f < 8; f++) acc += eav[f] * sWe1[f * 64 + k];
            sT[k * 128 + el4] = (eg4 < NE) ? f2b(fmaxf(acc, 0.f)) : (u16)0;
        }
    }
    __syncthreads();   // last barrier — K-loop below is barrier-free

    f32x4 msg[4];
    #pragma unroll
    for (int rt = 0; rt < 4; rt++) msg[rt] = (f32x4){0.f, 0.f, 0.f, 0.f};

    // coalesced per-lane B pointers for this wave's column quarter
    const u16* gB0 = Bt2 + (0 * 4 + cq) * 512 + lane * 8;
    const u16* gB1 = Bt2 + (1 * 4 + cq) * 512 + lane * 8;

    short8 bf0 = *(const short8*)gB0;
    short8 bf1 = *(const short8*)gB1;
    const f32x4 zero = (f32x4){0.f, 0.f, 0.f, 0.f};

    for (int kc = 0; kc < 64; kc++) {
        short8 bn0 = *(const short8*)(gB0 + (kc + 1) * 4096);
        short8 bn1 = *(const short8*)(gB1 + (kc + 1) * 4096);

        ushort4 tkv[4];
        #pragma unroll
        for (int rt = 0; rt < 4; rt++)
            tkv[rt] = *(const ushort4*)&sT[kc * 128 + rh * 64 + rt * 16 + quad * 4];

        #pragma unroll
        for (int rt = 0; rt < 4; rt++) {
            f32x4 q = __builtin_amdgcn_mfma_f32_16x16x32_bf16(xa[rt][0], bf0, zero, 0, 0, 0);
            q = __builtin_amdgcn_mfma_f32_16x16x32_bf16(xa[rt][1], bf1, q, 0, 0, 0);
            msg[rt][0] += b2f(tkv[rt].x) * q[0];
            msg[rt][1] += b2f(tkv[rt].y) * q[1];
            msg[rt][2] += b2f(tkv[rt].z) * q[2];
            msg[rt][3] += b2f(tkv[rt].w) * q[3];
        }
        bf0 = bn0; bf1 = bn1;
    }
    // bias chunk (kc=64): t = 1 -> msg += q
    #pragma unroll
    for (int rt = 0; rt < 4; rt++) {
        f32x4 q = __builtin_amdgcn_mfma_f32_16x16x32_bf16(xa[rt][0], bf0, zero, 0, 0, 0);
        q = __builtin_amdgcn_mfma_f32_16x16x32_bf16(xa[rt][1], bf1, q, 0, 0, 0);
        #pragma unroll
        for (int r = 0; r < 4; r++) msg[rt][r] += q[r];
    }

    // epilogue: row = rh*64 + rt*16 + quad*4 + r, col = cq*16 + ll; scatter into agg[dst]
    #pragma unroll
    for (int rt = 0; rt < 4; rt++) {
        #pragma unroll
        for (int r = 0; r < 4; r++) {
            int el = rh * 64 + rt * 16 + quad * 4 + r;
            int eg = e0 + el;
            if (eg < NE) {
                int d = sDst[el];
                atomicAdd(&agg[d * 64 + cq * 16 + ll], msg[rt][r]);
            }
        }
    }
}

// ---- GRU via MFMA (round-8 verified; staging vectorized) ---------------------------------
__global__ __launch_bounds__(256) void k_gru(const u16* __restrict__ x1b,
                                             const float* __restrict__ agg,
                                             const float* __restrict__ Wroot,
                                             const float* __restrict__ bconv,
                                             const float* __restrict__ Wi,
                                             const float* __restrict__ Wh,
                                             const float* __restrict__ bi,
                                             const float* __restrict__ bh,
                                             const int* __restrict__ batch,
                                             float* __restrict__ pooled) {
    __shared__ __align__(16) u16 sWi[192 * 72];
    __shared__ __align__(16) u16 sWh[192 * 72];
    __shared__ __align__(16) u16 sX2[64 * 72];
    __shared__ int sBatch[64];
    const int tid = threadIdx.x;
    const int lane = tid & 63, wv = tid >> 6;
    const int ll = lane & 15, quad = lane >> 4;
    const int n0 = blockIdx.x * 64;

    for (int idx = tid; idx < 64 * 16; idx += 256) {
        int n = idx & 63, k4 = (idx >> 6) * 4;
        ushort4 a;
        a.x = f2b(Wroot[(k4 + 0) * 64 + n]);
        a.y = f2b(Wroot[(k4 + 1) * 64 + n]);
        a.z = f2b(Wroot[(k4 + 2) * 64 + n]);
        a.w = f2b(Wroot[(k4 + 3) * 64 + n]);
        *(ushort4*)&sWi[n * 72 + k4] = a;
    }
    if (tid < 64) {
        int n = n0 + tid;
        sBatch[tid] = (n < NN) ? batch[n] : -1;
    }
    __syncthreads();

    short8 ha[2];
    {
        int n = n0 + wv * 16 + ll;
        #pragma unroll
        for (int kc = 0; kc < 2; kc++) {
            if (n < NN) ha[kc] = *(const short8*)(x1b + n * 64 + kc * 32 + quad * 8);
            else        ha[kc] = (short8){0,0,0,0,0,0,0,0};
        }
    }
    f32x4 acc1[4];
    #pragma unroll
    for (int c = 0; c < 4; c++) acc1[c] = (f32x4){0.f, 0.f, 0.f, 0.f};
    #pragma unroll
    for (int kc = 0; kc < 2; kc++) {
        #pragma unroll
        for (int c = 0; c < 4; c++) {
            short8 b = *(const short8*)&sWi[(c * 16 + ll) * 72 + kc * 32 + quad * 8];
            acc1[c] = __builtin_amdgcn_mfma_f32_16x16x32_bf16(ha[kc], b, acc1[c], 0, 0, 0);
        }
    }
    #pragma unroll
    for (int c = 0; c < 4; c++) {
        int col = c * 16 + ll;
        float bcv = bconv[col];
        #pragma unroll
        for (int r = 0; r < 4; r++) {
            int row = wv * 16 + quad * 4 + r;
            int n = n0 + row;
            float v = 0.f;
            if (n < NN) v = fmaxf(acc1[c][r] + agg[n * 64 + col] + bcv, 0.f);
            sX2[row * 72 + col] = f2b(v);
        }
    }
    __syncthreads();

    for (int idx = tid; idx < 192 * 16; idx += 256) {
        int j = idx >> 4, i4 = (idx & 15) * 4;
        float4 wi4 = *(const float4*)&Wi[j * 64 + i4];
        float4 wh4 = *(const float4*)&Wh[j * 64 + i4];
        ushort4 a, b;
        a.x = f2b(wi4.x); a.y = f2b(wi4.y); a.z = f2b(wi4.z); a.w = f2b(wi4.w);
        b.x = f2b(wh4.x); b.y = f2b(wh4.y); b.z = f2b(wh4.z); b.w = f2b(wh4.w);
        *(ushort4*)&sWi[j * 72 + i4] = a;
        *(ushort4*)&sWh[j * 72 + i4] = b;
    }
    __syncthreads();

    short8 xa[2];
    #pragma unroll
    for (int kc = 0; kc < 2; kc++)
        xa[kc] = *(const short8*)&sX2[(wv * 16 + ll) * 72 + kc * 32 + quad * 8];

    f32x4 agi[12], agh[12];
    #pragma unroll
    for (int c = 0; c < 12; c++) { agi[c] = (f32x4){0.f,0.f,0.f,0.f}; agh[c] = (f32x4){0.f,0.f,0.f,0.f}; }
    #pragma unroll
    for (int kc = 0; kc < 2; kc++) {
        #pragma unroll
        for (int c = 0; c < 12; c++) {
            short8 bi8 = *(const short8*)&sWi[(c * 16 + ll) * 72 + kc * 32 + quad * 8];
            short8 bh8 = *(const short8*)&sWh[(c * 16 + ll) * 72 + kc * 32 + quad * 8];
            agi[c] = __builtin_amdgcn_mfma_f32_16x16x32_bf16(xa[kc], bi8, agi[c], 0, 0, 0);
            agh[c] = __builtin_amdgcn_mfma_f32_16x16x32_bf16(ha[kc], bh8, agh[c], 0, 0, 0);
        }
    }

    float hnv[4][4];
    #pragma unroll
    for (int c0 = 0; c0 < 4; c0++) {
        int d = c0 * 16 + ll;
        float bir = bi[d],        bhr = bh[d];
        float biz = bi[64 + d],   bhz = bh[64 + d];
        float bin = bi[128 + d],  bhn = bh[128 + d];
        #pragma unroll
        for (int r = 0; r < 4; r++) {
            int row = wv * 16 + quad * 4 + r;
            int n = n0 + row;
            float gir = agi[c0][r] + bir,     ghr = agh[c0][r] + bhr;
            float giz = agi[c0 + 4][r] + biz, ghz = agh[c0 + 4][r] + bhz;
            float gin = agi[c0 + 8][r] + bin, ghn = agh[c0 + 8][r] + bhn;
            float rg = 1.f / (1.f + __expf(-(gir + ghr)));
            float zg = 1.f / (1.f + __expf(-(giz + ghz)));
            float ng = tanhf(gin + rg * ghn);
            float hv = (n < NN) ? b2f(x1b[n * 64 + d]) : 0.f;
            hnv[c0][r] = (n < NN) ? ((1.f - zg) * ng + zg * hv) : 0.f;
        }
    }
    __syncthreads();

    float* hbuf = (float*)sWi;
    #pragma unroll
    for (int c0 = 0; c0 < 4; c0++) {
        int d = c0 * 16 + ll;
        #pragma unroll
        for (int r = 0; r < 4; r++) {
            int row = wv * 16 + quad * 4 + r;
            hbuf[row * 65 + d] = hnv[c0][r];
        }
    }
    __syncthreads();

    {
        int d = lane;
        float sum = 0.f;
        int pb = sBatch[wv * 16];
        #pragma unroll
        for (int rr = 0; rr < 16; rr++) {
            int row = wv * 16 + rr;
            int b = sBatch[row];
            float v = hbuf[row * 65 + d];
            if (b != pb) {
                if (pb >= 0) atomicAdd(&pooled[pb * 64 + d], sum);
                sum = v; pb = b;
            } else {
                sum += v;
            }
        }
        if (pb >= 0) atomicAdd(&pooled[pb * 64 + d], sum);
    }
}

// ---- heads: two 3-layer MLPs over pooled; output FLOAT32 ---------------------------------
__global__ __launch_bounds__(256) void k_heads(const float* __restrict__ pooled,
                                               const float* __restrict__ W11, const float* __restrict__ b11,
                                               const float* __restrict__ W12, const float* __restrict__ b12,
                                               const float* __restrict__ W13, const float* __restrict__ b13,
                                               const float* __restrict__ W21, const float* __restrict__ b21,
                                               const float* __restrict__ W22, const float* __restrict__ b22,
                                               const float* __restrict__ W23, const float* __restrict__ b23,
                                               float* __restrict__ out) {
    __shared__ float sV[4][64];
    __shared__ float sA[4][64];
    int tid = threadIdx.x, lane = tid & 63, wv = tid >> 6;
    int g = blockIdx.x * 4 + wv;
    if (g >= NG) return;
    float p = pooled[g * 64 + lane];
    sV[wv][lane] = p;
    float y[2];
    const float* W1s[2] = {W11, W21}; const float* b1s[2] = {b11, b21};
    const float* W2s[2] = {W12, W22}; const float* b2s[2] = {b12, b22};
    const float* W3s[2] = {W13, W23}; const float* b3s[2] = {b13, b23};
    #pragma unroll
    for (int hd = 0; hd < 2; hd++) {
        float a = b1s[hd][lane];
        #pragma unroll 8
        for (int i = 0; i < 64; i++) a += sV[wv][i] * W1s[hd][i * 64 + lane];
        a = fmaxf(a, 0.f);
        sA[wv][lane] = a;
        float a2 = b2s[hd][lane];
        #pragma unroll 8
        for (int i = 0; i < 64; i++) a2 += sA[wv][i] * W2s[hd][i * 64 + lane];
        a2 = fmaxf(a2, 0.f);
        float part = a2 * W3s[hd][lane];
        #pragma unroll
        for (int m = 32; m > 0; m >>= 1) part += __shfl_xor(part, m, 64);
        y[hd] = part + b3s[hd][0];
    }
    if (lane == 0) {
        out[g * 2 + 0] = y[0];
        out[g * 2 + 1] = y[1];
    }
}

extern "C" void kernel_launch(void* const* d_in, const int* in_sizes, int n_in,
                              void* d_out, int out_size, void* d_ws, size_t ws_size,
                              hipStream_t stream) {
    const float* x     = (const float*)d_in[0];
    const int* eidx    = (const int*)d_in[1];
    const float* ea    = (const float*)d_in[2];
    const int* batch   = (const int*)d_in[3];
    const float* W0    = (const float*)d_in[4];  const float* b0    = (const float*)d_in[5];
    const float* We1   = (const float*)d_in[6];  const float* be1   = (const float*)d_in[7];
    const float* We2   = (const float*)d_in[8];  const float* be2   = (const float*)d_in[9];
    const float* Wroot = (const float*)d_in[10]; const float* bconv = (const float*)d_in[11];
    const float* Wi    = (const float*)d_in[12]; const float* Wh    = (const float*)d_in[13];
    const float* bi    = (const float*)d_in[14]; const float* bh    = (const float*)d_in[15];
    const float* W11   = (const float*)d_in[16]; const float* b11   = (const float*)d_in[17];
    const float* W12   = (const float*)d_in[18]; const float* b12   = (const float*)d_in[19];
    const float* W13   = (const float*)d_in[20]; const float* b13   = (const float*)d_in[21];
    const float* W21   = (const float*)d_in[22]; const float* b21   = (const float*)d_in[23];
    const float* W22   = (const float*)d_in[24]; const float* b22   = (const float*)d_in[25];
    const float* W23   = (const float*)d_in[26]; const float* b23   = (const float*)d_in[27];
    float* out = (float*)d_out;

    // workspace: total 10,388,480 B
    char* ws = (char*)d_ws;
    float* agg    = (float*)(ws);                       // 6,400,000 B
    u16*   x1b    = (u16*)(ws + 6400000);               // 3,200,000 B
    u16*   Bt2    = (u16*)(ws + 9600000);               //   532,480 B
    float* pooled = (float*)(ws + 10132480);            //   256,000 B

    hipLaunchKernelGGL(k_pre, dim3(7274), dim3(256), 0, stream,
                       x, W0, b0, x1b, We2, be2, agg, pooled, Bt2);
    hipLaunchKernelGGL(k_msg, dim3(782), dim3(512), 0, stream, ea, eidx, We1, be1, x1b, Bt2, agg);
    hipLaunchKernelGGL(k_gru, dim3(391), dim3(256), 0, stream, x1b, agg, Wroot, bconv,
                       Wi, Wh, bi, bh, batch, pooled);
    hipLaunchKernelGGL(k_heads, dim3(250), dim3(256), 0, stream, pooled,
                       W11, b11, W12, b12, W13, b13, W21, b21, W22, b22, W23, b23, out);
}

// Round 15
// 237.783 us; speedup vs baseline: 1.3948x; 1.3948x over previous
//
#include <hip/hip_runtime.h>
#include <hip/hip_bf16.h>

#define NN 25000
#define NE 100000
#define FIN 32
#define DD 64
#define NG 1000

typedef unsigned short u16;
typedef __attribute__((ext_vector_type(8))) short short8;
typedef __attribute__((ext_vector_type(4))) float f32x4;

__device__ __forceinline__ float b2f(u16 u) {
    union { unsigned int i; float f; } v; v.i = ((unsigned int)u) << 16; return v.f;
}
__device__ __forceinline__ u16 f2b(float f) {
    __hip_bfloat16 h = __float2bfloat16(f);
    return __builtin_bit_cast(u16, h);
}
// edge_index may be int64 read as int32 words: odd words would all be 0.
__device__ __forceinline__ bool idx_is_i64(const int* e) {
    return (e[1] == 0) & (e[3] == 0) & (e[5] == 0) & (e[7] == 0) & (e[9] == 0);
}
__device__ __forceinline__ int ld_src(const int* e, int i, bool i64) {
    return i64 ? e[2 * i] : e[i];
}
__device__ __forceinline__ int ld_dst(const int* e, int i, bool i64) {
    return i64 ? e[2 * (NE + i)] : e[NE + i];
}

// ---- fused pre-pass: blocks [0,6250) = lin0; blocks [6250,7274) = Bt2 build + zeroing ----
// Bt2 fragment-major: idx = kc*4096 + (s*4+c)*512 + lane*8 + j  holds
// B[k = kc*64 + s*32 + (lane>>4)*8 + j][o = c*16 + (lane&15)]  (r>=4096 -> be2 rows).
__global__ __launch_bounds__(256) void k_pre(const float* __restrict__ x,
                                             const float* __restrict__ W0,
                                             const float* __restrict__ b0,
                                             u16* __restrict__ x1b,
                                             const float* __restrict__ We2,
                                             const float* __restrict__ be2,
                                             float* __restrict__ agg,
                                             float* __restrict__ pooled,
                                             u16* __restrict__ Bt2) {
    __shared__ float sW[FIN * DD];
    __shared__ float sx[4 * FIN];
    if (blockIdx.x < 6250) {
        int tid = threadIdx.x;
        for (int i = tid; i < FIN * DD; i += 256) sW[i] = W0[i];
        int nbase = blockIdx.x * 4;
        for (int i = tid; i < 4 * FIN; i += 256) {
            int nl = i >> 5, f = i & 31;
            int n = nbase + nl;
            sx[i] = (n < NN) ? x[n * FIN + f] : 0.f;
        }
        __syncthreads();
        int lane = tid & 63, nl = tid >> 6;
        int n = nbase + nl;
        if (n < NN) {
            float acc = b0[lane];
            #pragma unroll
            for (int f = 0; f < FIN; f++) acc += sx[nl * FIN + f] * sW[f * DD + lane];
            x1b[n * DD + lane] = f2b(fmaxf(acc, 0.f));
        }
    } else {
        int tid = (blockIdx.x - 6250) * 256 + threadIdx.x;
        int stride = 1024 * 256;
        for (int idx = tid; idx < 65 * 4096; idx += stride) {
            int kc = idx >> 12;
            int rem = idx & 4095;
            int f = rem >> 9;
            int ln = (rem >> 3) & 63;
            int j = idx & 7;
            int s = f >> 2, c = f & 3;
            int o = c * 16 + (ln & 15);
            int r = kc * 64 + s * 32 + (ln >> 4) * 8 + j;
            float v = (r < 4096) ? We2[(r >> 6) * 4096 + (r & 63) * 64 + o]
                                 : be2[(r - 4096) * 64 + o];
            Bt2[idx] = f2b(v);
        }
        for (int idx = tid; idx < NN * DD; idx += stride) agg[idx] = 0.f;
        for (int idx = tid; idx < NG * DD; idx += stride) pooled[idx] = 0.f;
    }
}

// ---- fused NNConv message GEMM + scatter -------------------------------------------------
// 512 threads = 8 waves: wave = (row-half rh, col-quarter cq). Per kc: q = Xs@W2[kc]
// (bf16 MFMA, fixed A-frags), msg += t[e,kc]*q. B direct from L2-resident Bt2 (coalesced,
// depth-1 register prefetch); K-loop barrier-free. sX/sT alias one LDS region:
// LDS = 18432 + 2048 + 256 + 512 = 21248 B -> 7 blocks/CU by LDS; wave cap -> 4 blocks.
// launch_bounds(512,4): VGPR cap 512 — compiler's natural ~44 regs, NO SPILL (r14's
// (512,8) forced 32 VGPR -> scratch spill, FETCH/WRITE doubled, 187 us).
__global__ __launch_bounds__(512, 4) void k_msg(const float* __restrict__ ea,
                                                const int* __restrict__ eidx,
                                                const float* __restrict__ We1,
                                                const float* __restrict__ be1,
                                                const u16* __restrict__ x1b,
                                                const u16* __restrict__ Bt2,
                                                float* __restrict__ agg) {
    __shared__ __align__(16) u16 sXT[128 * 72];  // phase1: sX rows; K-loop: sT bf16 [64][128]
    __shared__ float sWe1[8 * 64];
    __shared__ float sbe1[64];
    __shared__ int sDst[128];
    const int tid = threadIdx.x;
    const int lane = tid & 63, wv = tid >> 6;
    const int ll = lane & 15, quad = lane >> 4;
    const int rh = wv >> 2, cq = wv & 3;       // row-half, col-quarter
    const int e0 = blockIdx.x * 128;
    const bool i64 = idx_is_i64(eidx);
    u16* sX = sXT;
    u16* sT = sXT;   // alias: sX is dead once A-fragments are hoisted

    if (tid < 512) sWe1[tid] = We1[tid];
    if (tid < 64) sbe1[tid] = be1[tid];
    if (tid < 128) sDst[tid] = (e0 + tid < NE) ? ld_dst(eidx, e0 + tid, i64) : 0;

    // phase 1: gather x1 rows (bf16) for 128 edges; each thread: 32 B of one row
    const int el4 = tid >> 2, seg = tid & 3;
    const int eg4 = e0 + el4;
    {
        if (eg4 < NE) {
            int sv = ld_src(eidx, eg4, i64);
            const u16* xr = x1b + sv * 64 + seg * 16;
            *(uint4*)&sX[el4 * 72 + seg * 16]     = *(const uint4*)(xr);
            *(uint4*)&sX[el4 * 72 + seg * 16 + 8] = *(const uint4*)(xr + 8);
        } else {
            uint4 z = make_uint4(0, 0, 0, 0);
            *(uint4*)&sX[el4 * 72 + seg * 16]     = z;
            *(uint4*)&sX[el4 * 72 + seg * 16 + 8] = z;
        }
    }
    float eav[8];
    if (eg4 < NE) {
        f32x4 v0 = *(const f32x4*)(ea + eg4 * 8);
        f32x4 v1 = *(const f32x4*)(ea + eg4 * 8 + 4);
        #pragma unroll
        for (int f = 0; f < 4; f++) { eav[f] = v0[f]; eav[4 + f] = v1[f]; }
    } else {
        #pragma unroll
        for (int f = 0; f < 8; f++) eav[f] = 0.f;
    }
    __syncthreads();

    // hoist fixed A-fragments BEFORE phase 2 (sT will overwrite sX)
    short8 xa[4][2];
    #pragma unroll
    for (int rt = 0; rt < 4; rt++)
        #pragma unroll
        for (int s = 0; s < 2; s++)
            xa[rt][s] = *(const short8*)&sX[(rh * 64 + rt * 16 + ll) * 72 + s * 32 + quad * 8];
    __syncthreads();   // all hoists complete before sT writes trample sX

    // phase 2: t[e,k] = relu(ea @ We1 + be1); each thread: 16 k-values of its edge (bf16)
    {
        int k0 = seg * 16;
        for (int kk = 0; kk < 16; kk++) {
            int k = k0 + kk;
            float acc = sbe1[k];
            #pragma unroll
            for (int f = 0; f < 8; f++) acc += eav[f] * sWe1[f * 64 + k];
            sT[k * 128 + el4] = (eg4 < NE) ? f2b(fmaxf(acc, 0.f)) : (u16)0;
        }
    }
    __syncthreads();   // last barrier — K-loop below is barrier-free

    f32x4 msg[4];
    #pragma unroll
    for (int rt = 0; rt < 4; rt++) msg[rt] = (f32x4){0.f, 0.f, 0.f, 0.f};

    // coalesced per-lane B pointers for this wave's column quarter
    const u16* gB0 = Bt2 + (0 * 4 + cq) * 512 + lane * 8;
    const u16* gB1 = Bt2 + (1 * 4 + cq) * 512 + lane * 8;

    short8 bf0 = *(const short8*)gB0;
    short8 bf1 = *(const short8*)gB1;
    const f32x4 zero = (f32x4){0.f, 0.f, 0.f, 0.f};

    for (int kc = 0; kc < 64; kc++) {
        short8 bn0 = *(const short8*)(gB0 + (kc + 1) * 4096);
        short8 bn1 = *(const short8*)(gB1 + (kc + 1) * 4096);

        ushort4 tkv[4];
        #pragma unroll
        for (int rt = 0; rt < 4; rt++)
            tkv[rt] = *(const ushort4*)&sT[kc * 128 + rh * 64 + rt * 16 + quad * 4];

        #pragma unroll
        for (int rt = 0; rt < 4; rt++) {
            f32x4 q = __builtin_amdgcn_mfma_f32_16x16x32_bf16(xa[rt][0], bf0, zero, 0, 0, 0);
            q = __builtin_amdgcn_mfma_f32_16x16x32_bf16(xa[rt][1], bf1, q, 0, 0, 0);
            msg[rt][0] += b2f(tkv[rt].x) * q[0];
            msg[rt][1] += b2f(tkv[rt].y) * q[1];
            msg[rt][2] += b2f(tkv[rt].z) * q[2];
            msg[rt][3] += b2f(tkv[rt].w) * q[3];
        }
        bf0 = bn0; bf1 = bn1;
    }
    // bias chunk (kc=64): t = 1 -> msg += q
    #pragma unroll
    for (int rt = 0; rt < 4; rt++) {
        f32x4 q = __builtin_amdgcn_mfma_f32_16x16x32_bf16(xa[rt][0], bf0, zero, 0, 0, 0);
        q = __builtin_amdgcn_mfma_f32_16x16x32_bf16(xa[rt][1], bf1, q, 0, 0, 0);
        #pragma unroll
        for (int r = 0; r < 4; r++) msg[rt][r] += q[r];
    }

    // epilogue: row = rh*64 + rt*16 + quad*4 + r, col = cq*16 + ll; scatter into agg[dst]
    #pragma unroll
    for (int rt = 0; rt < 4; rt++) {
        #pragma unroll
        for (int r = 0; r < 4; r++) {
            int el = rh * 64 + rt * 16 + quad * 4 + r;
            int eg = e0 + el;
            if (eg < NE) {
                int d = sDst[el];
                atomicAdd(&agg[d * 64 + cq * 16 + ll], msg[rt][r]);
            }
        }
    }
}

// ---- GRU via MFMA (round-8 verified; staging vectorized) ---------------------------------
__global__ __launch_bounds__(256) void k_gru(const u16* __restrict__ x1b,
                                             const float* __restrict__ agg,
                                             const float* __restrict__ Wroot,
                                             const float* __restrict__ bconv,
                                             const float* __restrict__ Wi,
                                             const float* __restrict__ Wh,
                                             const float* __restrict__ bi,
                                             const float* __restrict__ bh,
                                             const int* __restrict__ batch,
                                             float* __restrict__ pooled) {
    __shared__ __align__(16) u16 sWi[192 * 72];
    __shared__ __align__(16) u16 sWh[192 * 72];
    __shared__ __align__(16) u16 sX2[64 * 72];
    __shared__ int sBatch[64];
    const int tid = threadIdx.x;
    const int lane = tid & 63, wv = tid >> 6;
    const int ll = lane & 15, quad = lane >> 4;
    const int n0 = blockIdx.x * 64;

    for (int idx = tid; idx < 64 * 16; idx += 256) {
        int n = idx & 63, k4 = (idx >> 6) * 4;
        ushort4 a;
        a.x = f2b(Wroot[(k4 + 0) * 64 + n]);
        a.y = f2b(Wroot[(k4 + 1) * 64 + n]);
        a.z = f2b(Wroot[(k4 + 2) * 64 + n]);
        a.w = f2b(Wroot[(k4 + 3) * 64 + n]);
        *(ushort4*)&sWi[n * 72 + k4] = a;
    }
    if (tid < 64) {
        int n = n0 + tid;
        sBatch[tid] = (n < NN) ? batch[n] : -1;
    }
    __syncthreads();

    short8 ha[2];
    {
        int n = n0 + wv * 16 + ll;
        #pragma unroll
        for (int kc = 0; kc < 2; kc++) {
            if (n < NN) ha[kc] = *(const short8*)(x1b + n * 64 + kc * 32 + quad * 8);
            else        ha[kc] = (short8){0,0,0,0,0,0,0,0};
        }
    }
    f32x4 acc1[4];
    #pragma unroll
    for (int c = 0; c < 4; c++) acc1[c] = (f32x4){0.f, 0.f, 0.f, 0.f};
    #pragma unroll
    for (int kc = 0; kc < 2; kc++) {
        #pragma unroll
        for (int c = 0; c < 4; c++) {
            short8 b = *(const short8*)&sWi[(c * 16 + ll) * 72 + kc * 32 + quad * 8];
            acc1[c] = __builtin_amdgcn_mfma_f32_16x16x32_bf16(ha[kc], b, acc1[c], 0, 0, 0);
        }
    }
    #pragma unroll
    for (int c = 0; c < 4; c++) {
        int col = c * 16 + ll;
        float bcv = bconv[col];
        #pragma unroll
        for (int r = 0; r < 4; r++) {
            int row = wv * 16 + quad * 4 + r;
            int n = n0 + row;
            float v = 0.f;
            if (n < NN) v = fmaxf(acc1[c][r] + agg[n * 64 + col] + bcv, 0.f);
            sX2[row * 72 + col] = f2b(v);
        }
    }
    __syncthreads();

    for (int idx = tid; idx < 192 * 16; idx += 256) {
        int j = idx >> 4, i4 = (idx & 15) * 4;
        float4 wi4 = *(const float4*)&Wi[j * 64 + i4];
        float4 wh4 = *(const float4*)&Wh[j * 64 + i4];
        ushort4 a, b;
        a.x = f2b(wi4.x); a.y = f2b(wi4.y); a.z = f2b(wi4.z); a.w = f2b(wi4.w);
        b.x = f2b(wh4.x); b.y = f2b(wh4.y); b.z = f2b(wh4.z); b.w = f2b(wh4.w);
        *(ushort4*)&sWi[j * 72 + i4] = a;
        *(ushort4*)&sWh[j * 72 + i4] = b;
    }
    __syncthreads();

    short8 xa[2];
    #pragma unroll
    for (int kc = 0; kc < 2; kc++)
        xa[kc] = *(const short8*)&sX2[(wv * 16 + ll) * 72 + kc * 32 + quad * 8];

    f32x4 agi[12], agh[12];
    #pragma unroll
    for (int c = 0; c < 12; c++) { agi[c] = (f32x4){0.f,0.f,0.f,0.f}; agh[c] = (f32x4){0.f,0.f,0.f,0.f}; }
    #pragma unroll
    for (int kc = 0; kc < 2; kc++) {
        #pragma unroll
        for (int c = 0; c < 12; c++) {
            short8 bi8 = *(const short8*)&sWi[(c * 16 + ll) * 72 + kc * 32 + quad * 8];
            short8 bh8 = *(const short8*)&sWh[(c * 16 + ll) * 72 + kc * 32 + quad * 8];
            agi[c] = __builtin_amdgcn_mfma_f32_16x16x32_bf16(xa[kc], bi8, agi[c], 0, 0, 0);
            agh[c] = __builtin_amdgcn_mfma_f32_16x16x32_bf16(ha[kc], bh8, agh[c], 0, 0, 0);
        }
    }

    float hnv[4][4];
    #pragma unroll
    for (int c0 = 0; c0 < 4; c0++) {
        int d = c0 * 16 + ll;
        float bir = bi[d],        bhr = bh[d];
        float biz = bi[64 + d],   bhz = bh[64 + d];
        float bin = bi[128 + d],  bhn = bh[128 + d];
        #pragma unroll
        for (int r = 0; r < 4; r++) {
            int row = wv * 16 + quad * 4 + r;
            int n = n0 + row;
            float gir = agi[c0][r] + bir,     ghr = agh[c0][r] + bhr;
            float giz = agi[c0 + 4][r] + biz, ghz = agh[c0 + 4][r] + bhz;
            float gin = agi[c0 + 8][r] + bin, ghn = agh[c0 + 8][r] + bhn;
            float rg = 1.f / (1.f + __expf(-(gir + ghr)));
            float zg = 1.f / (1.f + __expf(-(giz + ghz)));
            float ng = tanhf(gin + rg * ghn);
            float hv = (n < NN) ? b2f(x1b[n * 64 + d]) : 0.f;
            hnv[c0][r] = (n < NN) ? ((1.f - zg) * ng + zg * hv) : 0.f;
        }
    }
    __syncthreads();

    float* hbuf = (float*)sWi;
    #pragma unroll
    for (int c0 = 0; c0 < 4; c0++) {
        int d = c0 * 16 + ll;
        #pragma unroll
        for (int r = 0; r < 4; r++) {
            int row = wv * 16 + quad * 4 + r;
            hbuf[row * 65 + d] = hnv[c0][r];
        }
    }
    __syncthreads();

    {
        int d = lane;
        float sum = 0.f;
        int pb = sBatch[wv * 16];
        #pragma unroll
        for (int rr = 0; rr < 16; rr++) {
            int row = wv * 16 + rr;
            int b = sBatch[row];
            float v = hbuf[row * 65 + d];
            if (b != pb) {
                if (pb >= 0) atomicAdd(&pooled[pb * 64 + d], sum);
                sum = v; pb = b;
            } else {
                sum += v;
            }
        }
        if (pb >= 0) atomicAdd(&pooled[pb * 64 + d], sum);
    }
}

// ---- heads: two 3-layer MLPs over pooled; output FLOAT32 ---------------------------------
__global__ __launch_bounds__(256) void k_heads(const float* __restrict__ pooled,
                                               const float* __restrict__ W11, const float* __restrict__ b11,
                                               const float* __restrict__ W12, const float* __restrict__ b12,
                                               const float* __restrict__ W13, const float* __restrict__ b13,
                                               const float* __restrict__ W21, const float* __restrict__ b21,
                                               const float* __restrict__ W22, const float* __restrict__ b22,
                                               const float* __restrict__ W23, const float* __restrict__ b23,
                                               float* __restrict__ out) {
    __shared__ float sV[4][64];
    __shared__ float sA[4][64];
    int tid = threadIdx.x, lane = tid & 63, wv = tid >> 6;
    int g = blockIdx.x * 4 + wv;
    if (g >= NG) return;
    float p = pooled[g * 64 + lane];
    sV[wv][lane] = p;
    float y[2];
    const float* W1s[2] = {W11, W21}; const float* b1s[2] = {b11, b21};
    const float* W2s[2] = {W12, W22}; const float* b2s[2] = {b12, b22};
    const float* W3s[2] = {W13, W23}; const float* b3s[2] = {b13, b23};
    #pragma unroll
    for (int hd = 0; hd < 2; hd++) {
        float a = b1s[hd][lane];
        #pragma unroll 8
        for (int i = 0; i < 64; i++) a += sV[wv][i] * W1s[hd][i * 64 + lane];
        a = fmaxf(a, 0.f);
        sA[wv][lane] = a;
        float a2 = b2s[hd][lane];
        #pragma unroll 8
        for (int i = 0; i < 64; i++) a2 += sA[wv][i] * W2s[hd][i * 64 + lane];
        a2 = fmaxf(a2, 0.f);
        float part = a2 * W3s[hd][lane];
        #pragma unroll
        for (int m = 32; m > 0; m >>= 1) part += __shfl_xor(part, m, 64);
        y[hd] = part + b3s[hd][0];
    }
    if (lane == 0) {
        out[g * 2 + 0] = y[0];
        out[g * 2 + 1] = y[1];
    }
}

extern "C" void kernel_launch(void* const* d_in, const int* in_sizes, int n_in,
                              void* d_out, int out_size, void* d_ws, size_t ws_size,
                              hipStream_t stream) {
    const float* x     = (const float*)d_in[0];
    const int* eidx    = (const int*)d_in[1];
    const float* ea    = (const float*)d_in[2];
    const int* batch   = (const int*)d_in[3];
    const float* W0    = (const float*)d_in[4];  const float* b0    = (const float*)d_in[5];
    const float* We1   = (const float*)d_in[6];  const float* be1   = (const float*)d_in[7];
    const float* We2   = (const float*)d_in[8];  const float* be2   = (const float*)d_in[9];
    const float* Wroot = (const float*)d_in[10]; const float* bconv = (const float*)d_in[11];
    const float* Wi    = (const float*)d_in[12]; const float* Wh    = (const float*)d_in[13];
    const float* bi    = (const float*)d_in[14]; const float* bh    = (const float*)d_in[15];
    const float* W11   = (const float*)d_in[16]; const float* b11   = (const float*)d_in[17];
    const float* W12   = (const float*)d_in[18]; const float* b12   = (const float*)d_in[19];
    const float* W13   = (const float*)d_in[20]; const float* b13   = (const float*)d_in[21];
    const float* W21   = (const float*)d_in[22]; const float* b21   = (const float*)d_in[23];
    const float* W22   = (const float*)d_in[24]; const float* b22   = (const float*)d_in[25];
    const float* W23   = (const float*)d_in[26]; const float* b23   = (const float*)d_in[27];
    float* out = (float*)d_out;

    // workspace: total 10,388,480 B
    char* ws = (char*)d_ws;
    float* agg    = (float*)(ws);                       // 6,400,000 B
    u16*   x1b    = (u16*)(ws + 6400000);               // 3,200,000 B
    u16*   Bt2    = (u16*)(ws + 9600000);               //   532,480 B
    float* pooled = (float*)(ws + 10132480);            //   256,000 B

    hipLaunchKernelGGL(k_pre, dim3(7274), dim3(256), 0, stream,
                       x, W0, b0, x1b, We2, be2, agg, pooled, Bt2);
    hipLaunchKernelGGL(k_msg, dim3(782), dim3(512), 0, stream, ea, eidx, We1, be1, x1b, Bt2, agg);
    hipLaunchKernelGGL(k_gru, dim3(391), dim3(256), 0, stream, x1b, agg, Wroot, bconv,
                       Wi, Wh, bi, bh, batch, pooled);
    hipLaunchKernelGGL(k_heads, dim3(250), dim3(256), 0, stream, pooled,
                       W11, b11, W12, b12, W13, b13, W21, b21, W22, b22, W23, b23, out);
}